// Round 1
// baseline (2054.792 us; speedup 1.0000x reference)
//
#include <hip/hip_runtime.h>
#include <math.h>

#define BATCH 8
#define CH 512
#define LEN 2048
#define NG 32
#define CPG 16                      // CH / NG
#define GROUP_ELEMS (CPG * LEN)     // 32768

#define BK 16
#define BM 64
#define BN 64
#define PAD 4                       // row stride 68 floats = 272B (16B-aligned)

// ---------------------------------------------------------------------------
// GroupNorm: one block per (batch, group); group region is 16*2048 contiguous
// ---------------------------------------------------------------------------
__global__ __launch_bounds__(256) void gn_kernel(const float* __restrict__ x,
                                                 const float* __restrict__ gw,
                                                 const float* __restrict__ gb,
                                                 float* __restrict__ h) {
    const int bg = blockIdx.x;
    const int b = bg >> 5;
    const int g = bg & 31;
    const size_t base = ((size_t)b * CH + (size_t)g * CPG) * LEN;
    const float* xp = x + base;

    float s = 0.f, s2 = 0.f;
    for (int i = threadIdx.x; i < GROUP_ELEMS; i += 256) {
        float v = xp[i];
        s += v;
        s2 = fmaf(v, v, s2);
    }
    #pragma unroll
    for (int off = 32; off > 0; off >>= 1) {
        s  += __shfl_down(s, off, 64);
        s2 += __shfl_down(s2, off, 64);
    }
    __shared__ float sm[2][4];
    const int lane = threadIdx.x & 63, wv = threadIdx.x >> 6;
    if (lane == 0) { sm[0][wv] = s; sm[1][wv] = s2; }
    __syncthreads();
    const float S  = sm[0][0] + sm[0][1] + sm[0][2] + sm[0][3];
    const float S2 = sm[1][0] + sm[1][1] + sm[1][2] + sm[1][3];
    const float mean = S * (1.f / GROUP_ELEMS);
    const float var  = S2 * (1.f / GROUP_ELEMS) - mean * mean;
    const float rstd = rsqrtf(var + 1e-6f);

    float* hp = h + base;
    for (int i = threadIdx.x; i < GROUP_ELEMS; i += 256) {
        const int c = g * CPG + (i >> 11);   // i / LEN
        hp[i] = (xp[i] - mean) * rstd * gw[c] + gb[c];
    }
}

// ---------------------------------------------------------------------------
// conv1x1: Out[b,o,l] = sum_c W[o,c] * Hin[b,c,l] + bias[o] (+ res[b,o,l])
// grid: (LEN/BN, CH/BM, BATCH), 256 threads, 4x4 microtile
// ---------------------------------------------------------------------------
__global__ __launch_bounds__(256) void conv_kernel(const float* __restrict__ W,
                                                   const float* __restrict__ bias,
                                                   const float* __restrict__ Hin,
                                                   const float* __restrict__ res,
                                                   float* __restrict__ Out) {
    __shared__ __align__(16) float As[BK][BM + PAD];   // [k][m]  W tile
    __shared__ __align__(16) float Bs[BK][BN + PAD];   // [k][n]  H tile
    const int b  = blockIdx.z;
    const int m0 = blockIdx.y * BM;
    const int n0 = blockIdx.x * BN;
    const float* Hb = Hin + (size_t)b * CH * LEN;
    const int t = threadIdx.x;
    const int tx = t & 15, ty = t >> 4;
    const int akk = t & 15, amm = t >> 4;   // A (W) load: 16-wide along c
    const int bnn = t & 63, bkk = t >> 6;   // B (H) load: 64-wide along l
    float acc[4][4] = {};

    for (int c0 = 0; c0 < CH; c0 += BK) {
        #pragma unroll
        for (int it = 0; it < 4; ++it) {
            const int mm = amm + it * 16;
            As[akk][mm] = W[(size_t)(m0 + mm) * CH + c0 + akk];
        }
        #pragma unroll
        for (int it = 0; it < 4; ++it) {
            const int kk = bkk + it * 4;
            Bs[kk][bnn] = Hb[(size_t)(c0 + kk) * LEN + n0 + bnn];
        }
        __syncthreads();
        #pragma unroll
        for (int kk = 0; kk < BK; ++kk) {
            const float4 a4 = *(const float4*)&As[kk][ty * 4];
            const float4 b4 = *(const float4*)&Bs[kk][tx * 4];
            const float av[4] = {a4.x, a4.y, a4.z, a4.w};
            const float bv[4] = {b4.x, b4.y, b4.z, b4.w};
            #pragma unroll
            for (int i = 0; i < 4; ++i)
                #pragma unroll
                for (int j = 0; j < 4; ++j)
                    acc[i][j] = fmaf(av[i], bv[j], acc[i][j]);
        }
        __syncthreads();
    }

    float* Ob = Out + (size_t)b * CH * LEN;
    const float* Rb = res ? res + (size_t)b * CH * LEN : nullptr;
    #pragma unroll
    for (int i = 0; i < 4; ++i) {
        const int o = m0 + ty * 4 + i;
        const float bb = bias[o];
        #pragma unroll
        for (int j = 0; j < 4; ++j) {
            const size_t idx = (size_t)o * LEN + n0 + tx * 4 + j;
            float v = acc[i][j] + bb;
            if (Rb) v += Rb[idx];
            Ob[idx] = v;
        }
    }
}

// ---------------------------------------------------------------------------
// scores: S[i,j] = scale * sum_c Q[c,i] * K[c,j]   (one batch)
// Q,K: (CH, LEN) row-major.  grid: (LEN/BN, LEN/BM)
// ---------------------------------------------------------------------------
__global__ __launch_bounds__(256) void scores_kernel(const float* __restrict__ Q,
                                                     const float* __restrict__ K,
                                                     float* __restrict__ S) {
    __shared__ __align__(16) float As[BK][BM + PAD];
    __shared__ __align__(16) float Bs[BK][BN + PAD];
    const int i0 = blockIdx.y * BM;
    const int j0 = blockIdx.x * BN;
    const int t = threadIdx.x;
    const int tx = t & 15, ty = t >> 4;
    const int mm = t & 63, kk0 = t >> 6;
    float acc[4][4] = {};

    for (int c0 = 0; c0 < CH; c0 += BK) {
        #pragma unroll
        for (int it = 0; it < 4; ++it) {
            const int kk = kk0 + it * 4;
            const size_t roff = (size_t)(c0 + kk) * LEN;
            As[kk][mm] = Q[roff + i0 + mm];
            Bs[kk][mm] = K[roff + j0 + mm];
        }
        __syncthreads();
        #pragma unroll
        for (int kk = 0; kk < BK; ++kk) {
            const float4 a4 = *(const float4*)&As[kk][ty * 4];
            const float4 b4 = *(const float4*)&Bs[kk][tx * 4];
            const float av[4] = {a4.x, a4.y, a4.z, a4.w};
            const float bv[4] = {b4.x, b4.y, b4.z, b4.w};
            #pragma unroll
            for (int i = 0; i < 4; ++i)
                #pragma unroll
                for (int j = 0; j < 4; ++j)
                    acc[i][j] = fmaf(av[i], bv[j], acc[i][j]);
        }
        __syncthreads();
    }

    const float scale = 0.04419417382415922f;   // 512^-0.5
    #pragma unroll
    for (int i = 0; i < 4; ++i)
        #pragma unroll
        for (int j = 0; j < 4; ++j)
            S[(size_t)(i0 + ty * 4 + i) * LEN + j0 + tx * 4 + j] = acc[i][j] * scale;
}

// ---------------------------------------------------------------------------
// softmax over each row of S (LEN x LEN), in place. one block per row.
// ---------------------------------------------------------------------------
__global__ __launch_bounds__(256) void softmax_kernel(float* __restrict__ S) {
    float* row = S + (size_t)blockIdx.x * LEN;
    const int t = threadIdx.x;
    float v[8];
    float mx = -3.4e38f;
    #pragma unroll
    for (int r = 0; r < 8; ++r) {
        v[r] = row[t + r * 256];
        mx = fmaxf(mx, v[r]);
    }
    #pragma unroll
    for (int off = 32; off > 0; off >>= 1)
        mx = fmaxf(mx, __shfl_down(mx, off, 64));
    __shared__ float sm[4];
    __shared__ float sm2[4];
    const int lane = t & 63, wv = t >> 6;
    if (lane == 0) sm[wv] = mx;
    __syncthreads();
    mx = fmaxf(fmaxf(sm[0], sm[1]), fmaxf(sm[2], sm[3]));

    float sum = 0.f;
    #pragma unroll
    for (int r = 0; r < 8; ++r) {
        v[r] = __expf(v[r] - mx);
        sum += v[r];
    }
    #pragma unroll
    for (int off = 32; off > 0; off >>= 1)
        sum += __shfl_down(sum, off, 64);
    if (lane == 0) sm2[wv] = sum;
    __syncthreads();
    sum = sm2[0] + sm2[1] + sm2[2] + sm2[3];
    const float inv = 1.f / sum;
    #pragma unroll
    for (int r = 0; r < 8; ++r)
        row[t + r * 256] = v[r] * inv;
}

// ---------------------------------------------------------------------------
// PV: Hout[c,i] = sum_j V[c,j] * P[i,j]   (one batch)
// V: (CH, LEN), P: (LEN, LEN) row-major.  grid: (LEN/BN, CH/BM)
// ---------------------------------------------------------------------------
__global__ __launch_bounds__(256) void pv_kernel(const float* __restrict__ V,
                                                 const float* __restrict__ P,
                                                 float* __restrict__ Hout) {
    __shared__ __align__(16) float As[BK][BM + PAD];   // [k=j][m=c]
    __shared__ __align__(16) float Bs[BK][BN + PAD];   // [k=j][n=i]
    const int m0 = blockIdx.y * BM;   // channel tile
    const int n0 = blockIdx.x * BN;   // i tile
    const int t = threadIdx.x;
    const int tx = t & 15, ty = t >> 4;
    const int lkk = t & 15, lrr = t >> 4;
    float acc[4][4] = {};

    for (int j0 = 0; j0 < LEN; j0 += BK) {
        #pragma unroll
        for (int it = 0; it < 4; ++it) {
            const int mm = lrr + it * 16;
            As[lkk][mm] = V[(size_t)(m0 + mm) * LEN + j0 + lkk];
        }
        #pragma unroll
        for (int it = 0; it < 4; ++it) {
            const int nn = lrr + it * 16;
            Bs[lkk][nn] = P[(size_t)(n0 + nn) * LEN + j0 + lkk];
        }
        __syncthreads();
        #pragma unroll
        for (int kk = 0; kk < BK; ++kk) {
            const float4 a4 = *(const float4*)&As[kk][ty * 4];
            const float4 b4 = *(const float4*)&Bs[kk][tx * 4];
            const float av[4] = {a4.x, a4.y, a4.z, a4.w};
            const float bv[4] = {b4.x, b4.y, b4.z, b4.w};
            #pragma unroll
            for (int i = 0; i < 4; ++i)
                #pragma unroll
                for (int j = 0; j < 4; ++j)
                    acc[i][j] = fmaf(av[i], bv[j], acc[i][j]);
        }
        __syncthreads();
    }

    #pragma unroll
    for (int i = 0; i < 4; ++i)
        #pragma unroll
        for (int j = 0; j < 4; ++j)
            Hout[(size_t)(m0 + ty * 4 + i) * LEN + n0 + tx * 4 + j] = acc[i][j];
}

// ---------------------------------------------------------------------------
extern "C" void kernel_launch(void* const* d_in, const int* in_sizes, int n_in,
                              void* d_out, int out_size, void* d_ws, size_t ws_size,
                              hipStream_t stream) {
    const float* x    = (const float*)d_in[0];
    const float* gn_w = (const float*)d_in[1];
    const float* gn_b = (const float*)d_in[2];
    const float* wq   = (const float*)d_in[3];
    const float* bq   = (const float*)d_in[4];
    const float* wk   = (const float*)d_in[5];
    const float* bk   = (const float*)d_in[6];
    const float* wv   = (const float*)d_in[7];
    const float* bv   = (const float*)d_in[8];
    const float* wo   = (const float*)d_in[9];
    const float* bo   = (const float*)d_in[10];
    float* out = (float*)d_out;
    float* ws  = (float*)d_ws;

    const size_t BCL = (size_t)BATCH * CH * LEN;
    float* Hbuf = ws;               // GroupNorm out; later reused as attention out
    float* Qb   = Hbuf + BCL;
    float* Kb   = Qb + BCL;
    float* Vb   = Kb + BCL;
    float* Sb   = Vb + BCL;         // LEN*LEN scores, reused per batch (stream-ordered)

    gn_kernel<<<BATCH * NG, 256, 0, stream>>>(x, gn_w, gn_b, Hbuf);

    const dim3 cgrid(LEN / BN, CH / BM, BATCH);
    conv_kernel<<<cgrid, 256, 0, stream>>>(wq, bq, Hbuf, nullptr, Qb);
    conv_kernel<<<cgrid, 256, 0, stream>>>(wk, bk, Hbuf, nullptr, Kb);
    conv_kernel<<<cgrid, 256, 0, stream>>>(wv, bv, Hbuf, nullptr, Vb);

    for (int b = 0; b < BATCH; ++b) {
        const size_t off = (size_t)b * CH * LEN;
        scores_kernel<<<dim3(LEN / BN, LEN / BM), 256, 0, stream>>>(Qb + off, Kb + off, Sb);
        softmax_kernel<<<LEN, 256, 0, stream>>>(Sb);
        pv_kernel<<<dim3(LEN / BN, CH / BM), 256, 0, stream>>>(Vb + off, Sb, Hbuf + off);
    }

    // output projection + residual, straight into d_out
    conv_kernel<<<cgrid, 256, 0, stream>>>(wo, bo, Hbuf, x, out);
}

// Round 2
// 342.864 us; speedup vs baseline: 5.9930x; 5.9930x over previous
//
#include <hip/hip_runtime.h>
#include <math.h>

#define BATCH 8
#define CH 512
#define LEN 2048
#define NG 32
#define CPG 16

typedef unsigned short u16;
typedef __bf16 bf16x8 __attribute__((ext_vector_type(8)));
typedef float f32x4 __attribute__((ext_vector_type(4)));

__device__ __forceinline__ u16 f2bf(float f) {
    union { float f; unsigned u; } c; c.f = f;
    unsigned r = c.u + 0x7fffu + ((c.u >> 16) & 1u);   // RNE
    return (u16)(r >> 16);
}
__device__ __forceinline__ float bf2f(u16 h) {
    union { unsigned u; float f; } c; c.u = ((unsigned)h) << 16;
    return c.f;
}
__device__ __forceinline__ void gload16(const u16* g, u16* l) {
    __builtin_amdgcn_global_load_lds(
        (const __attribute__((address_space(1))) unsigned int*)g,
        (__attribute__((address_space(3))) unsigned int*)l, 16, 0, 0);
}

// ---------------------------------------------------------------------------
// Weight fp32 -> bf16 (4 matrices of 512x512)
// ---------------------------------------------------------------------------
__global__ __launch_bounds__(256) void wconv4(const float* __restrict__ w0, const float* __restrict__ w1,
                                              const float* __restrict__ w2, const float* __restrict__ w3,
                                              u16* __restrict__ o0, u16* __restrict__ o1,
                                              u16* __restrict__ o2, u16* __restrict__ o3) {
    const float* s; u16* d;
    switch (blockIdx.y) {
        case 0: s = w0; d = o0; break;
        case 1: s = w1; d = o1; break;
        case 2: s = w2; d = o2; break;
        default: s = w3; d = o3; break;
    }
    const int i = blockIdx.x * 256 + threadIdx.x;     // 65536 float4 chunks
    float4 f = ((const float4*)s)[i];
    ushort4 o = make_ushort4(f2bf(f.x), f2bf(f.y), f2bf(f.z), f2bf(f.w));
    ((ushort4*)d)[i] = o;
}

// ---------------------------------------------------------------------------
// GroupNorm stats: per (b,g) mean/rstd -> per-channel scale/shift tables
// ---------------------------------------------------------------------------
__global__ __launch_bounds__(256) void gn_stats(const float* __restrict__ x,
                                                const float* __restrict__ gw,
                                                const float* __restrict__ gb,
                                                float* __restrict__ gnA,
                                                float* __restrict__ gnB) {
    const int b = blockIdx.x >> 5, g = blockIdx.x & 31;
    const float4* xp = (const float4*)(x + ((size_t)b * CH + (size_t)g * CPG) * LEN);
    float s = 0.f, s2 = 0.f;
    for (int i = threadIdx.x; i < (CPG * LEN) / 4; i += 256) {
        float4 v = xp[i];
        s += v.x + v.y + v.z + v.w;
        s2 = fmaf(v.x, v.x, fmaf(v.y, v.y, fmaf(v.z, v.z, fmaf(v.w, v.w, s2))));
    }
    #pragma unroll
    for (int off = 32; off > 0; off >>= 1) {
        s  += __shfl_down(s, off, 64);
        s2 += __shfl_down(s2, off, 64);
    }
    __shared__ float sm[2][4];
    const int lane = threadIdx.x & 63, wv = threadIdx.x >> 6;
    if (lane == 0) { sm[0][wv] = s; sm[1][wv] = s2; }
    __syncthreads();
    if (threadIdx.x < CPG) {
        const float S  = sm[0][0] + sm[0][1] + sm[0][2] + sm[0][3];
        const float S2 = sm[1][0] + sm[1][1] + sm[1][2] + sm[1][3];
        const float mean = S * (1.f / (CPG * LEN));
        const float var  = S2 * (1.f / (CPG * LEN)) - mean * mean;
        const float rstd = rsqrtf(var + 1e-6f);
        const int c = g * CPG + threadIdx.x;
        const float sc = rstd * gw[c];
        gnA[b * CH + c] = sc;
        gnB[b * CH + c] = gb[c] - mean * sc;
    }
}

// ---------------------------------------------------------------------------
// Apply GN + transpose: Ht[b][l][c] (bf16) from x[b][c][l] (fp32)
// grid (LEN/64, CH/64, B), 256 thr, LDS 64x65 fp32 tile
// ---------------------------------------------------------------------------
__global__ __launch_bounds__(256) void gn_apply_t(const float* __restrict__ x,
                                                  const float* __restrict__ gnA,
                                                  const float* __restrict__ gnB,
                                                  u16* __restrict__ Ht) {
    __shared__ float tile[64][65];
    const int b = blockIdx.z, c0 = blockIdx.y * 64, l0 = blockIdx.x * 64;
    const int t = threadIdx.x, tl = t & 63, tr = t >> 6;
    #pragma unroll 4
    for (int i = 0; i < 16; ++i) {
        const int c = tr + i * 4;
        const float a = gnA[b * CH + c0 + c];
        const float sh = gnB[b * CH + c0 + c];
        tile[c][tl] = x[((size_t)b * CH + c0 + c) * LEN + l0 + tl] * a + sh;
    }
    __syncthreads();
    #pragma unroll 4
    for (int i = 0; i < 16; ++i) {
        const int l = tr + i * 4;
        Ht[((size_t)b * LEN + l0 + l) * CH + c0 + tl] = f2bf(tile[tl][l]);
    }
}

// ---------------------------------------------------------------------------
// MFMA GEMM (B^T form): C[m][n] = sum_k A[m][k]*B[n][k], A:(M,K) B:(N,K) bf16
// 128x128 tile, BK=32, 256 thr (4 waves of 64x64), global_load_lds staging.
// Epilogue modes select output layout/dtype/bias/residual.
// ---------------------------------------------------------------------------
#define EPI_TRANS_BIAS 0   // bf16 Out[n*ldo+m] = acc + bias[m]    (Q,K convs)
#define EPI_NORM_BIAS  1   // bf16 Out[m*ldo+n] = acc + bias[m]    (V conv)
#define EPI_SCALE      2   // bf16 Out[m*ldo+n] = acc * alpha      (scores)
#define EPI_TRANS      3   // bf16 Out[n*ldo+m] = acc              (PV)
#define EPI_FINAL      4   // f32  Out[m*ldo+n] = acc + bias[m] + res (out conv)

template <int MODE>
__global__ __launch_bounds__(256) void gemm_bt(
    const u16* __restrict__ A, int lda, long long strideAb,
    const u16* __restrict__ B, int ldb, long long strideBb,
    void* __restrict__ Out, int ldo, long long strideOb,
    const float* __restrict__ bias,
    const float* __restrict__ res, long long strideRb,
    int K, float alpha) {
    __shared__ u16 As[128 * 32];
    __shared__ u16 Bs[128 * 32];
    const int b = blockIdx.z;
    const int n0 = blockIdx.x * 128, m0 = blockIdx.y * 128;
    A += (size_t)b * strideAb;
    B += (size_t)b * strideBb;
    const int t = threadIdx.x;
    const int lane = t & 63, wid = t >> 6;

    // staging: chunk c = t + r*256 covers row=c>>2, kq=c&3 (16B each)
    const int rowL = t >> 2, kq = t & 3;
    const u16* gA0 = A + (size_t)(m0 + rowL) * lda + kq * 8;
    const u16* gA1 = gA0 + (size_t)64 * lda;
    const u16* gB0 = B + (size_t)(n0 + rowL) * ldb + kq * 8;
    const u16* gB1 = gB0 + (size_t)64 * ldb;
    u16* lA0 = As + t * 8;
    u16* lA1 = As + 2048 + t * 8;
    u16* lB0 = Bs + t * 8;
    u16* lB1 = Bs + 2048 + t * 8;

    f32x4 acc[4][4];
    #pragma unroll
    for (int i = 0; i < 4; ++i)
        #pragma unroll
        for (int j = 0; j < 4; ++j)
            acc[i][j] = (f32x4){0.f, 0.f, 0.f, 0.f};

    const int mf = (wid & 1) * 64 + (lane & 15);
    const int nf = (wid >> 1) * 64 + (lane & 15);
    const int kf = (lane >> 4) * 8;

    for (int k0 = 0; k0 < K; k0 += 32) {
        gload16(gA0, lA0);
        gload16(gA1, lA1);
        gload16(gB0, lB0);
        gload16(gB1, lB1);
        gA0 += 32; gA1 += 32; gB0 += 32; gB1 += 32;
        __syncthreads();          // drains vmcnt (global_load_lds) at barrier
        bf16x8 af[4], bfr[4];
        #pragma unroll
        for (int i = 0; i < 4; ++i) af[i]  = *(const bf16x8*)(As + (mf + i * 16) * 32 + kf);
        #pragma unroll
        for (int j = 0; j < 4; ++j) bfr[j] = *(const bf16x8*)(Bs + (nf + j * 16) * 32 + kf);
        #pragma unroll
        for (int i = 0; i < 4; ++i)
            #pragma unroll
            for (int j = 0; j < 4; ++j)
                acc[i][j] = __builtin_amdgcn_mfma_f32_16x16x32_bf16(af[i], bfr[j], acc[i][j], 0, 0, 0);
        __syncthreads();
    }

    const int quad = lane >> 4, col = lane & 15;
    const int wm = (wid & 1) * 64, wn = (wid >> 1) * 64;

    if (MODE == EPI_FINAL) {
        float* O = (float*)Out + (size_t)b * strideOb;
        const float* R = res + (size_t)b * strideRb;
        #pragma unroll
        for (int i = 0; i < 4; ++i) {
            const int mb = m0 + wm + i * 16 + quad * 4;
            #pragma unroll
            for (int r = 0; r < 4; ++r) {
                const float bb = bias[mb + r];
                #pragma unroll
                for (int j = 0; j < 4; ++j) {
                    const int n = n0 + wn + j * 16 + col;
                    const size_t idx = (size_t)(mb + r) * ldo + n;
                    O[idx] = acc[i][j][r] + bb + R[idx];
                }
            }
        }
    } else if (MODE == EPI_SCALE || MODE == EPI_NORM_BIAS) {
        u16* O = (u16*)Out + (size_t)b * strideOb;
        #pragma unroll
        for (int i = 0; i < 4; ++i) {
            const int mb = m0 + wm + i * 16 + quad * 4;
            #pragma unroll
            for (int r = 0; r < 4; ++r) {
                const float add = (MODE == EPI_NORM_BIAS) ? bias[mb + r] : 0.f;
                #pragma unroll
                for (int j = 0; j < 4; ++j) {
                    const int n = n0 + wn + j * 16 + col;
                    float v = acc[i][j][r];
                    v = (MODE == EPI_SCALE) ? v * alpha : v + add;
                    O[(size_t)(mb + r) * ldo + n] = f2bf(v);
                }
            }
        }
    } else {  // EPI_TRANS_BIAS / EPI_TRANS : Out[n*ldo + m], 4 regs contiguous in m
        u16* O = (u16*)Out + (size_t)b * strideOb;
        #pragma unroll
        for (int i = 0; i < 4; ++i) {
            const int mb = m0 + wm + i * 16 + quad * 4;
            float4 bb4 = make_float4(0.f, 0.f, 0.f, 0.f);
            if (MODE == EPI_TRANS_BIAS) bb4 = *(const float4*)&bias[mb];
            #pragma unroll
            for (int j = 0; j < 4; ++j) {
                const int n = n0 + wn + j * 16 + col;
                ushort4 pk = make_ushort4(f2bf(acc[i][j][0] + bb4.x),
                                          f2bf(acc[i][j][1] + bb4.y),
                                          f2bf(acc[i][j][2] + bb4.z),
                                          f2bf(acc[i][j][3] + bb4.w));
                *(ushort4*)&O[(size_t)n * ldo + mb] = pk;
            }
        }
    }
}

// ---------------------------------------------------------------------------
// softmax over rows of bf16 S (in place). grid = B*LEN blocks, 256 thr.
// ---------------------------------------------------------------------------
__global__ __launch_bounds__(256) void softmax_bf16(u16* __restrict__ S) {
    u16* row = S + (size_t)blockIdx.x * LEN;
    const int t = threadIdx.x;
    ushort4 u0 = *(const ushort4*)&row[t * 8];
    ushort4 u1 = *(const ushort4*)&row[t * 8 + 4];
    float v[8] = {bf2f(u0.x), bf2f(u0.y), bf2f(u0.z), bf2f(u0.w),
                  bf2f(u1.x), bf2f(u1.y), bf2f(u1.z), bf2f(u1.w)};
    float mx = -3.4e38f;
    #pragma unroll
    for (int r = 0; r < 8; ++r) mx = fmaxf(mx, v[r]);
    #pragma unroll
    for (int off = 32; off > 0; off >>= 1) mx = fmaxf(mx, __shfl_down(mx, off, 64));
    __shared__ float sm[4], sm2[4];
    const int lane = t & 63, wv = t >> 6;
    if (lane == 0) sm[wv] = mx;
    __syncthreads();
    mx = fmaxf(fmaxf(sm[0], sm[1]), fmaxf(sm[2], sm[3]));
    float sum = 0.f;
    #pragma unroll
    for (int r = 0; r < 8; ++r) { v[r] = __expf(v[r] - mx); sum += v[r]; }
    #pragma unroll
    for (int off = 32; off > 0; off >>= 1) sum += __shfl_down(sum, off, 64);
    if (lane == 0) sm2[wv] = sum;
    __syncthreads();
    const float inv = 1.f / (sm2[0] + sm2[1] + sm2[2] + sm2[3]);
    u0 = make_ushort4(f2bf(v[0] * inv), f2bf(v[1] * inv), f2bf(v[2] * inv), f2bf(v[3] * inv));
    u1 = make_ushort4(f2bf(v[4] * inv), f2bf(v[5] * inv), f2bf(v[6] * inv), f2bf(v[7] * inv));
    *(ushort4*)&row[t * 8] = u0;
    *(ushort4*)&row[t * 8 + 4] = u1;
}

// ---------------------------------------------------------------------------
extern "C" void kernel_launch(void* const* d_in, const int* in_sizes, int n_in,
                              void* d_out, int out_size, void* d_ws, size_t ws_size,
                              hipStream_t stream) {
    const float* x    = (const float*)d_in[0];
    const float* gn_w = (const float*)d_in[1];
    const float* gn_b = (const float*)d_in[2];
    const float* wq   = (const float*)d_in[3];
    const float* bq   = (const float*)d_in[4];
    const float* wk   = (const float*)d_in[5];
    const float* bk   = (const float*)d_in[6];
    const float* wv   = (const float*)d_in[7];
    const float* bv   = (const float*)d_in[8];
    const float* wo   = (const float*)d_in[9];
    const float* bo   = (const float*)d_in[10];
    float* out = (float*)d_out;

    char* p = (char*)d_ws;
    const size_t WSZ = (size_t)CH * CH * 2;          // 512 KB per weight
    const size_t HSZ = (size_t)BATCH * CH * LEN * 2; // 16.78 MB
    u16* Wqb = (u16*)p; p += WSZ;
    u16* Wkb = (u16*)p; p += WSZ;
    u16* Wvb = (u16*)p; p += WSZ;
    u16* Wob = (u16*)p; p += WSZ;
    u16* Ht  = (u16*)p; p += HSZ;   // GN out [b][l][c]; later reused as PV out
    u16* Qt  = (u16*)p; p += HSZ;   // [b][l][c]
    u16* Kt  = (u16*)p; p += HSZ;   // [b][l][c]
    u16* Vb  = (u16*)p; p += HSZ;   // [b][c][l]
    u16* Sb  = (u16*)p; p += (size_t)BATCH * LEN * LEN * 2;  // 67 MB
    float* gnA = (float*)p; p += (size_t)BATCH * CH * 4;
    float* gnB = (float*)p;

    const long long sH = (long long)LEN * CH;   // per-batch stride of [l][c] bufs
    const long long sV = (long long)CH * LEN;
    const long long sS = (long long)LEN * LEN;
    const float scale = 0.04419417382415922f;   // 512^-0.5

    wconv4<<<dim3(256, 4), 256, 0, stream>>>(wq, wk, wv, wo, Wqb, Wkb, Wvb, Wob);
    gn_stats<<<BATCH * NG, 256, 0, stream>>>(x, gn_w, gn_b, gnA, gnB);
    gn_apply_t<<<dim3(LEN / 64, CH / 64, BATCH), 256, 0, stream>>>(x, gnA, gnB, Ht);

    // Q,K convs -> transposed bf16 [l][c]
    gemm_bt<EPI_TRANS_BIAS><<<dim3(16, 4, 8), 256, 0, stream>>>(
        Wqb, CH, 0, Ht, CH, sH, Qt, CH, sH, bq, nullptr, 0, CH, 0.f);
    gemm_bt<EPI_TRANS_BIAS><<<dim3(16, 4, 8), 256, 0, stream>>>(
        Wkb, CH, 0, Ht, CH, sH, Kt, CH, sH, bk, nullptr, 0, CH, 0.f);
    // V conv -> normal bf16 [c][l]
    gemm_bt<EPI_NORM_BIAS><<<dim3(16, 4, 8), 256, 0, stream>>>(
        Wvb, CH, 0, Ht, CH, sH, Vb, LEN, sV, bv, nullptr, 0, CH, 0.f);
    // scores: S[i][j] = scale * sum_c Qt[i][c]*Kt[j][c]
    gemm_bt<EPI_SCALE><<<dim3(16, 16, 8), 256, 0, stream>>>(
        Qt, CH, sH, Kt, CH, sH, Sb, LEN, sS, nullptr, nullptr, 0, CH, scale);
    softmax_bf16<<<BATCH * LEN, 256, 0, stream>>>(Sb);
    // PV: Hattn[c][i] = sum_j V[c][j]*P[i][j] -> transposed into Ht [i][c]
    gemm_bt<EPI_TRANS><<<dim3(16, 4, 8), 256, 0, stream>>>(
        Vb, LEN, sV, Sb, LEN, sS, Ht, CH, sH, nullptr, nullptr, 0, LEN, 0.f);
    // out conv + bias + residual -> fp32 d_out
    gemm_bt<EPI_FINAL><<<dim3(16, 4, 8), 256, 0, stream>>>(
        Wob, CH, 0, Ht, CH, sH, out, LEN, sV, bo, x, sV, CH, 0.f);
}